// Round 1
// baseline (868.672 us; speedup 1.0000x reference)
//
#include <hip/hip_runtime.h>

#define N_NODES 50000
#define N_EDGES 1600000
#define D_FEAT 32

// Kernel 1: out = (1 + eps) * node_feat   (vectorized float4)
__global__ void gine_init_out(const float* __restrict__ node_feat,
                              const float* __restrict__ eps,
                              float* __restrict__ out) {
    int i = blockIdx.x * blockDim.x + threadIdx.x;
    const int n4 = N_NODES * D_FEAT / 4;
    float scale = 1.0f + eps[0];
    if (i < n4) {
        float4 v = ((const float4*)node_feat)[i];
        v.x *= scale; v.y *= scale; v.z *= scale; v.w *= scale;
        ((float4*)out)[i] = v;
    }
}

// Kernel 2: per (edge, 4-feature group): m = relu(node_feat[src] + edge_feat),
// scatter-add into out[dst]. 8 threads per edge, float4 per thread.
__global__ void gine_edge_scatter(const float* __restrict__ node_feat,
                                  const float* __restrict__ edge_feat,
                                  const int* __restrict__ src,
                                  const int* __restrict__ dst,
                                  float* __restrict__ out) {
    int t = blockIdx.x * blockDim.x + threadIdx.x;
    int e = t >> 3;        // edge index
    int g = t & 7;         // which float4 within the 32-feature row
    if (e >= N_EDGES) return;

    int s = src[e];
    int d = dst[e];

    float4 nf = ((const float4*)node_feat)[s * 8 + g];
    float4 ef = ((const float4*)edge_feat)[(size_t)e * 8 + g];

    float4 m;
    m.x = fmaxf(nf.x + ef.x, 0.0f);
    m.y = fmaxf(nf.y + ef.y, 0.0f);
    m.z = fmaxf(nf.z + ef.z, 0.0f);
    m.w = fmaxf(nf.w + ef.w, 0.0f);

    float* op = out + (size_t)d * D_FEAT + g * 4;
    unsafeAtomicAdd(op + 0, m.x);
    unsafeAtomicAdd(op + 1, m.y);
    unsafeAtomicAdd(op + 2, m.z);
    unsafeAtomicAdd(op + 3, m.w);
}

extern "C" void kernel_launch(void* const* d_in, const int* in_sizes, int n_in,
                              void* d_out, int out_size, void* d_ws, size_t ws_size,
                              hipStream_t stream) {
    const float* node_feat = (const float*)d_in[0];
    const float* edge_feat = (const float*)d_in[1];
    const float* eps       = (const float*)d_in[2];
    const int*   src       = (const int*)d_in[3];
    const int*   dst       = (const int*)d_in[4];
    float* out = (float*)d_out;

    // Init out with residual term (also clears the 0xAA poison).
    {
        int n4 = N_NODES * D_FEAT / 4;
        int block = 256;
        int grid = (n4 + block - 1) / block;
        gine_init_out<<<grid, block, 0, stream>>>(node_feat, eps, out);
    }

    // Edge scatter: 8 threads per edge.
    {
        long long total = (long long)N_EDGES * 8;
        int block = 256;
        int grid = (int)((total + block - 1) / block);
        gine_edge_scatter<<<grid, block, 0, stream>>>(node_feat, edge_feat, src, dst, out);
    }
}

// Round 2
// 556.540 us; speedup vs baseline: 1.5608x; 1.5608x over previous
//
#include <hip/hip_runtime.h>

#define N_NODES 50000
#define N_EDGES 1600000
#define D_FEAT 32
#define SCAN_BLOCK 1024
#define N_SCAN_BLOCKS ((N_NODES + SCAN_BLOCK - 1) / SCAN_BLOCK)  // 49

// ws layout (int units):
//   cnt   [0, N)              edge count per dst node
//   excl  [N, 2N)             per-block exclusive scan of cnt
//   bsum  [2N, 2N+64)         per-scan-block totals
//   bsumx [2N+64, 2N+128)     exclusive scan of bsum
//   off   [2N+128, 3N+128)    global exclusive offsets (bin starts)
//   cur   [3N+128, 4N+128)    mutable cursors; after scatter == bin ends
//   eidx  [4N+128, 4N+128+E)  edge ids sorted by dst
#define WS_CNT   0
#define WS_EXCL  (N_NODES)
#define WS_BSUM  (2 * N_NODES)
#define WS_BSUMX (2 * N_NODES + 64)
#define WS_OFF   (2 * N_NODES + 128)
#define WS_CUR   (3 * N_NODES + 128)
#define WS_EIDX  (4 * N_NODES + 128)

__global__ void zero_counts(int* __restrict__ cnt) {
    int i = blockIdx.x * blockDim.x + threadIdx.x;
    if (i < N_NODES) cnt[i] = 0;
}

__global__ void histogram_dst(const int* __restrict__ dst, int* __restrict__ cnt) {
    int e = blockIdx.x * blockDim.x + threadIdx.x;
    if (e < N_EDGES) atomicAdd(&cnt[dst[e]], 1);
}

// Per-block Hillis-Steele exclusive scan; writes per-element exclusive prefix
// (within block) and the block total.
__global__ void scan_blocks(const int* __restrict__ cnt,
                            int* __restrict__ excl,
                            int* __restrict__ bsum) {
    __shared__ int lds[SCAN_BLOCK];
    int tid = threadIdx.x;
    int i = blockIdx.x * SCAN_BLOCK + tid;
    int v = (i < N_NODES) ? cnt[i] : 0;
    int sum = v;
    lds[tid] = v;
    __syncthreads();
    for (int ofs = 1; ofs < SCAN_BLOCK; ofs <<= 1) {
        int t = (tid >= ofs) ? lds[tid - ofs] : 0;
        __syncthreads();
        sum += t;
        lds[tid] = sum;
        __syncthreads();
    }
    if (i < N_NODES) excl[i] = sum - v;
    if (tid == SCAN_BLOCK - 1) bsum[blockIdx.x] = lds[SCAN_BLOCK - 1];
}

__global__ void scan_bsums(const int* __restrict__ bsum, int* __restrict__ bsumx) {
    if (blockIdx.x == 0 && threadIdx.x == 0) {
        int r = 0;
        for (int b = 0; b < N_SCAN_BLOCKS; ++b) { bsumx[b] = r; r += bsum[b]; }
    }
}

__global__ void finalize_off(const int* __restrict__ excl,
                             const int* __restrict__ bsumx,
                             int* __restrict__ off,
                             int* __restrict__ cur) {
    int i = blockIdx.x * SCAN_BLOCK + threadIdx.x;
    if (i < N_NODES) {
        int o = excl[i] + bsumx[blockIdx.x];
        off[i] = o;
        cur[i] = o;
    }
}

__global__ void scatter_edges(const int* __restrict__ dst,
                              int* __restrict__ cur,
                              int* __restrict__ eidx) {
    int e = blockIdx.x * blockDim.x + threadIdx.x;
    if (e < N_EDGES) {
        int p = atomicAdd(&cur[dst[e]], 1);
        eidx[p] = e;
    }
}

// 8 threads per node; thread g owns float4 column group g. Walks the node's
// dst-sorted edge list, accumulates relu(node_feat[src] + edge_feat) in
// registers, writes out = (1+eps)*node_feat + acc. No float atomics.
__global__ void aggregate(const float* __restrict__ node_feat,
                          const float* __restrict__ edge_feat,
                          const int* __restrict__ src,
                          const float* __restrict__ eps,
                          const int* __restrict__ off,
                          const int* __restrict__ cur,
                          const int* __restrict__ eidx,
                          float* __restrict__ out) {
    int t = blockIdx.x * blockDim.x + threadIdx.x;
    int n = t >> 3;
    int g = t & 7;
    if (n >= N_NODES) return;

    int start = off[n];
    int end = cur[n];  // after scatter, cur[n] == off[n] + count[n]

    float4 acc = make_float4(0.f, 0.f, 0.f, 0.f);
    for (int i = start; i < end; ++i) {
        int e = eidx[i];          // same address for all 8 lanes -> broadcast
        int s = src[e];           // L2-resident gather
        float4 ef = ((const float4*)edge_feat)[(size_t)e * 8 + g];
        float4 nf = ((const float4*)node_feat)[s * 8 + g];
        acc.x += fmaxf(nf.x + ef.x, 0.f);
        acc.y += fmaxf(nf.y + ef.y, 0.f);
        acc.z += fmaxf(nf.z + ef.z, 0.f);
        acc.w += fmaxf(nf.w + ef.w, 0.f);
    }

    float scale = 1.0f + eps[0];
    float4 h = ((const float4*)node_feat)[n * 8 + g];
    float4 o;
    o.x = scale * h.x + acc.x;
    o.y = scale * h.y + acc.y;
    o.z = scale * h.z + acc.z;
    o.w = scale * h.w + acc.w;
    ((float4*)out)[n * 8 + g] = o;
}

extern "C" void kernel_launch(void* const* d_in, const int* in_sizes, int n_in,
                              void* d_out, int out_size, void* d_ws, size_t ws_size,
                              hipStream_t stream) {
    const float* node_feat = (const float*)d_in[0];
    const float* edge_feat = (const float*)d_in[1];
    const float* eps       = (const float*)d_in[2];
    const int*   src       = (const int*)d_in[3];
    const int*   dst       = (const int*)d_in[4];
    float* out = (float*)d_out;

    int* ws = (int*)d_ws;
    int* cnt   = ws + WS_CNT;
    int* excl  = ws + WS_EXCL;
    int* bsum  = ws + WS_BSUM;
    int* bsumx = ws + WS_BSUMX;
    int* off   = ws + WS_OFF;
    int* cur   = ws + WS_CUR;
    int* eidx  = ws + WS_EIDX;

    const int B = 256;

    zero_counts<<<(N_NODES + B - 1) / B, B, 0, stream>>>(cnt);
    histogram_dst<<<(N_EDGES + B - 1) / B, B, 0, stream>>>(dst, cnt);
    scan_blocks<<<N_SCAN_BLOCKS, SCAN_BLOCK, 0, stream>>>(cnt, excl, bsum);
    scan_bsums<<<1, 64, 0, stream>>>(bsum, bsumx);
    finalize_off<<<N_SCAN_BLOCKS, SCAN_BLOCK, 0, stream>>>(excl, bsumx, off, cur);
    scatter_edges<<<(N_EDGES + B - 1) / B, B, 0, stream>>>(dst, cur, eidx);

    long long total = (long long)N_NODES * 8;
    aggregate<<<(int)((total + B - 1) / B), B, 0, stream>>>(
        node_feat, edge_feat, src, eps, off, cur, eidx, out);
}